// Round 1
// baseline (109.055 us; speedup 1.0000x reference)
//
#include <hip/hip_runtime.h>

// Multiprototypes: per-row squared distances to the 3 centers of the row's
// label, min-distance mean (loss1) and entropy-masked min-distance mean (loss2).
//
// B=262144, C=1000, K=3, D=64 (f32). HBM-bound: ~66 MB read -> ~10.4 us floor.
//
// Mapping: 16 lanes per row (one float4 each over D=64), 4 rows/wave,
// 4 waves/block, grid-strided so each block handles B/2048=128 rows.
// Per-block partial sums -> d_ws; 1-block finalize kernel writes out[0..1].

#define TH   0.95f
#define EPSF 1e-12f
#define NBLK 2048
#define BLK  256

__global__ __launch_bounds__(BLK, 8) void mp_main(
    const float* __restrict__ x,        // [B, 64]
    const int*   __restrict__ labels,   // [B]
    const float* __restrict__ centers,  // [1000, 3, 64]
    float*       __restrict__ partials, // [3 * gridDim.x]
    int B)
{
    const int tid  = threadIdx.x;
    const int lane = tid & 63;
    const int wave = tid >> 6;       // 0..3
    const int sub  = lane & 15;      // float4 slot within the row
    const int rsub = lane >> 4;      // row-within-wave 0..3

    const float4* __restrict__ x4 = (const float4*)x;
    const float4* __restrict__ c4 = (const float4*)centers;

    const int rows_per_block = B / NBLK;     // 128
    const int iters = rows_per_block / 16;   // 8 (16 rows per block-iter)
    const int row0 = blockIdx.x * rows_per_block;

    float s1 = 0.f, s2 = 0.f, sc = 0.f;

    for (int t = 0; t < iters; ++t) {
        const int row = row0 + t * 16 + wave * 4 + rsub;

        // coalesced: the wave reads 4 contiguous rows = 1024 B
        const float4 xv = x4[row * 16 + sub];
        const int lab = labels[row];         // 16 lanes same addr -> broadcast

        const float4* cb = c4 + lab * 48 + sub;  // lab*(K=3)*(16 float4/row)
        float a0, a1, a2;
        {
            float4 cv = cb[0];
            float dx = xv.x - cv.x, dy = xv.y - cv.y, dz = xv.z - cv.z, dw = xv.w - cv.w;
            a0 = dx * dx + dy * dy + dz * dz + dw * dw;
        }
        {
            float4 cv = cb[16];
            float dx = xv.x - cv.x, dy = xv.y - cv.y, dz = xv.z - cv.z, dw = xv.w - cv.w;
            a1 = dx * dx + dy * dy + dz * dz + dw * dw;
        }
        {
            float4 cv = cb[32];
            float dx = xv.x - cv.x, dy = xv.y - cv.y, dz = xv.z - cv.z, dw = xv.w - cv.w;
            a2 = dx * dx + dy * dy + dz * dz + dw * dw;
        }

        // 16-lane butterfly: every lane of the group ends with full row sums
        #pragma unroll
        for (int m = 1; m <= 8; m <<= 1) {
            a0 += __shfl_xor(a0, m);
            a1 += __shfl_xor(a1, m);
            a2 += __shfl_xor(a2, m);
        }

        const float mn  = fminf(a0, fminf(a1, a2));
        const float mx  = fmaxf(a0, fmaxf(a1, a2));
        const float mid = a0 + a1 + a2 - mn - mx;   // second smallest

        const float d0 = mn + EPSF, d1 = mid + EPSF;
        const float p  = d0 / (d0 + d1);            // p <= 0.5, strictly > 0
        const float q  = 1.f - p;
        const float ent = -(p * __log2f(p) + q * __log2f(q));
        const float msk = (ent <= TH) ? 1.f : 0.f;

        const float w = (sub == 0) ? 1.f : 0.f;     // count each row once
        s1 += w * mn;
        s2 += w * msk * mn;
        sc += w * msk;
    }

    // full-wave (64) butterfly reduce
    #pragma unroll
    for (int m = 1; m <= 32; m <<= 1) {
        s1 += __shfl_xor(s1, m);
        s2 += __shfl_xor(s2, m);
        sc += __shfl_xor(sc, m);
    }

    __shared__ float red[3][4];
    if (lane == 0) { red[0][wave] = s1; red[1][wave] = s2; red[2][wave] = sc; }
    __syncthreads();
    if (tid == 0) {
        partials[blockIdx.x]              = red[0][0] + red[0][1] + red[0][2] + red[0][3];
        partials[NBLK + blockIdx.x]       = red[1][0] + red[1][1] + red[1][2] + red[1][3];
        partials[2 * NBLK + blockIdx.x]   = red[2][0] + red[2][1] + red[2][2] + red[2][3];
    }
}

__global__ __launch_bounds__(BLK) void mp_final(
    const float* __restrict__ partials, float* __restrict__ out, float invB)
{
    const int tid  = threadIdx.x;
    const int lane = tid & 63;
    const int wave = tid >> 6;

    float s1 = 0.f, s2 = 0.f, sc = 0.f;
    for (int i = tid; i < NBLK; i += BLK) {
        s1 += partials[i];
        s2 += partials[NBLK + i];
        sc += partials[2 * NBLK + i];
    }
    #pragma unroll
    for (int m = 1; m <= 32; m <<= 1) {
        s1 += __shfl_xor(s1, m);
        s2 += __shfl_xor(s2, m);
        sc += __shfl_xor(sc, m);
    }
    __shared__ float red[3][4];
    if (lane == 0) { red[0][wave] = s1; red[1][wave] = s2; red[2][wave] = sc; }
    __syncthreads();
    if (tid == 0) {
        float t1 = red[0][0] + red[0][1] + red[0][2] + red[0][3];
        float t2 = red[1][0] + red[1][1] + red[1][2] + red[1][3];
        float t3 = red[2][0] + red[2][1] + red[2][2] + red[2][3];
        out[0] = t1 * invB;    // loss1 = mean(min_pos)
        out[1] = t2 / t3;      // loss2 = masked mean
    }
}

extern "C" void kernel_launch(void* const* d_in, const int* in_sizes, int n_in,
                              void* d_out, int out_size, void* d_ws, size_t ws_size,
                              hipStream_t stream) {
    const float* x       = (const float*)d_in[0];
    const int*   labels  = (const int*)d_in[1];
    const float* centers = (const float*)d_in[2];
    float* out      = (float*)d_out;
    float* partials = (float*)d_ws;   // 3*NBLK floats = 24 KB
    const int B = in_sizes[1];        // 262144

    mp_main<<<NBLK, BLK, 0, stream>>>(x, labels, centers, partials, B);
    mp_final<<<1, BLK, 0, stream>>>(partials, out, 1.0f / (float)B);
}